// Round 4
// baseline (3373.499 us; speedup 1.0000x reference)
//
#include <hip/hip_runtime.h>
#include <stdint.h>

// GRUClassifier: B=128, T=512, V=50000, D=U=256, 3U=768
// Persistent pipelined kernel, 64 blocks = 8 groups (16 samples) x 8 stages.
// R4: latency-structured steps -- raw lgkm-only barriers (no vmcnt drain),
// LDS double-buffer (1 barrier/step), register prefetch of ring operands with
// counted vmcnt waits, chunked flag protocol (poll/publish/drain every CH=4).

#define TT 512
#define RX 16   // xp ring depth (steps)
#define RH 64   // h ring depth (steps)
#define CH 4    // flag chunk

typedef __bf16 bf16x8 __attribute__((ext_vector_type(8)));
typedef float f32x4 __attribute__((ext_vector_type(4)));
typedef int i32x4 __attribute__((ext_vector_type(4)));

#define FLAGS_BYTES (128*256)
#define XPRING_E ((size_t)RX*768*16)      // bf16 elems per (g,l)
#define HRING_E  ((size_t)RH*16*256)      // bf16 elems per (g,l)
#define WS_XP_OFF ((size_t)FLAGS_BYTES)
#define WS_H_OFF  (WS_XP_OFF + (size_t)32*XPRING_E*2)
#define WS_HF_OFF (WS_H_OFF  + (size_t)32*HRING_E*2)

struct Params {
  const int* tokens;
  const float* emb;
  const float* Wx[4];
  const float* Wh[4];
  const float* bx[4];
  const float* bh[4];
  uint8_t* ws;
};

#define SCOPE_AGENT __HIP_MEMORY_SCOPE_AGENT

__device__ __forceinline__ uint32_t* flagp(uint8_t* ws, int kind, int g, int l){
  return (uint32_t*)(ws + ((size_t)(kind*32 + g*4 + l) * 256));
}
__device__ __forceinline__ uint32_t aload(uint32_t* p){
  return __hip_atomic_load(p, __ATOMIC_RELAXED, SCOPE_AGENT);
}
__device__ __forceinline__ void astore(uint32_t* p, uint32_t v){
  __hip_atomic_store(p, v, __ATOMIC_RELAXED, SCOPE_AGENT);
}
__device__ __forceinline__ void st_coh_b64(void* p, unsigned long long v){
  asm volatile("global_store_dwordx2 %0, %1, off sc0 sc1" :: "v"(p), "v"(v) : "memory");
}
__device__ __forceinline__ void st_coh_b128(void* p, i32x4 v){
  asm volatile("global_store_dwordx4 %0, %1, off sc0 sc1" :: "v"(p), "v"(v) : "memory");
}
__device__ __forceinline__ unsigned long long ld_coh_b64(const void* p){
  unsigned long long r;
  asm volatile("global_load_dwordx2 %0, %1, off sc0 sc1" : "=v"(r) : "v"(p));
  return r;
}
__device__ __forceinline__ i32x4 ld_coh_b128(const void* p){
  i32x4 r;
  asm volatile("global_load_dwordx4 %0, %1, off sc0 sc1" : "=v"(r) : "v"(p));
  return r;
}
#define WAITVM(N) asm volatile("s_waitcnt vmcnt(" #N ")" ::: "memory")
#define BARRIER_LGKM() asm volatile("s_waitcnt lgkmcnt(0)\n\ts_barrier" ::: "memory")

__device__ __forceinline__ unsigned short f2b(float f){
  __bf16 b = (__bf16)f; unsigned short u; __builtin_memcpy(&u, &b, 2); return u;
}
__device__ __forceinline__ float b2f(unsigned short u){
  __bf16 b; __builtin_memcpy(&b, &u, 2); return (float)b;
}
__device__ __forceinline__ f32x4 up4(unsigned long long q){
  f32x4 r;
  #pragma unroll
  for (int i=0;i<4;++i) r[i] = b2f((unsigned short)(q >> (16*i)));
  return r;
}
__device__ __forceinline__ unsigned long long pk4(f32x4 v){
  unsigned long long q = 0;
  #pragma unroll
  for (int i=0;i<4;++i) q |= ((unsigned long long)f2b(v[i])) << (16*i);
  return q;
}
__device__ __forceinline__ float sigf(float x){ return 1.f/(1.f + __expf(-x)); }
__device__ __forceinline__ float tanh_(float x){ return 2.f/(1.f + __expf(-2.f*x)) - 1.f; }

__global__ __launch_bounds__(512) void gru_pipeline(Params p){
  const int bid = blockIdx.x;
  const int g = bid >> 3;          // group: samples [16g, 16g+16)
  const int s = bid & 7;           // stage slot
  const int l = s >> 1;            // layer
  const bool isXp = (s & 1) == 0;
  const int tid = threadIdx.x;
  const int w = tid >> 6;          // wave 0..7
  const int lane = tid & 63;
  const int lg = lane >> 4;        // k-subgroup 0..3
  const int lc = lane & 15;        // row/col selector

  __shared__ int dead;
  __shared__ __align__(16) unsigned short sbuf[2][16*256]; // operand double-buffer
  if (tid == 0) dead = 0;
  int budget = 1 << 22;

  if (isXp) {
    // ---------------- XP stage: xp = x @ Wx + (bx [+bh for z/r]) ----------------
    const float* W = p.Wx[l];
    bf16x8 wx[6][8];               // wave owns cols [w*96, w*96+96)
    #pragma unroll
    for (int nt=0; nt<6; ++nt){
      const int col = w*96 + nt*16 + lc;
      #pragma unroll
      for (int kt=0; kt<8; ++kt){
        const int k0 = kt*32 + lg*8;
        bf16x8 v;
        #pragma unroll
        for (int e=0; e<8; ++e) v[e] = (__bf16)W[(size_t)(k0+e)*768 + col];
        wx[nt][kt] = v;
      }
    }
    float bias[6];
    #pragma unroll
    for (int nt=0; nt<6; ++nt){
      const int col = w*96 + nt*16 + lc;
      bias[nt] = p.bx[l][col] + (col < 512 ? p.bh[l][col] : 0.f);
    }
    uint32_t* prodXp = flagp(p.ws, 0, g, l);
    uint32_t* prodH  = (l>0) ? flagp(p.ws, 1, g, l-1) : nullptr;
    uint32_t* consXp = flagp(p.ws, 2, g, l);
    uint32_t* consH  = (l>0) ? flagp(p.ws, 3, g, l-1) : nullptr;
    __bf16* xr = (__bf16*)(p.ws + WS_XP_OFF) + (size_t)(g*4+l)*XPRING_E;
    const __bf16* hr = (l>0) ? ((const __bf16*)(p.ws + WS_H_OFF) + (size_t)(g*4+(l-1))*HRING_E) : nullptr;
    uint32_t consSeen = 0, prodSeen = 0;
    const int sm = tid >> 5, sc = tid & 31;   // staging row 0..15, chunk 0..31
    const int sidx = (sm*256 + sc*8) ^ ((sm&7)<<3);

    // prologue: stage slot 0 into sbuf[0]
    if (l > 0){
      if (tid == 0){
        while (prodSeen < 1u){
          prodSeen = aload(prodH);
          if (prodSeen < 1u){ if(--budget<0){dead=1;break;} __builtin_amdgcn_s_sleep(2); }
        }
      }
      __syncthreads();
      if (!dead){
        i32x4 v = ld_coh_b128(hr + (size_t)sm*256 + sc*8);
        WAITVM(0); __builtin_amdgcn_sched_barrier(0);
        *(i32x4*)&sbuf[0][sidx] = v;
      }
    } else {
      const int tok = p.tokens[(size_t)(g*16+sm)*TT];
      const float* er = p.emb + (size_t)tok*256 + sc*8;
      const float4 u0 = *(const float4*)er;
      const float4 u1 = *(const float4*)(er+4);
      bf16x8 v;
      v[0]=(__bf16)u0.x; v[1]=(__bf16)u0.y; v[2]=(__bf16)u0.z; v[3]=(__bf16)u0.w;
      v[4]=(__bf16)u1.x; v[5]=(__bf16)u1.y; v[6]=(__bf16)u1.z; v[7]=(__bf16)u1.w;
      *(bf16x8*)&sbuf[0][sidx] = v;
    }

    for (int t=0; t<TT; ++t){
      const bool bnd = (t & (CH-1)) == 0;
      if (bnd){
        __syncthreads();           // drains aged ring stores (>=1 step old)
        if (tid == 0){
          if (l > 0){
            const uint32_t need = (uint32_t)((t+CH+1 < TT) ? t+CH+1 : TT);
            while (prodSeen < need){
              prodSeen = aload(prodH);
              if (prodSeen < need){ if(--budget<0){dead=1;break;} __builtin_amdgcn_s_sleep(2); }
            }
          }
          if (t + CH - 1 >= RX && !dead){
            const uint32_t need2 = (uint32_t)(t + CH - RX);
            while (consSeen < need2){
              consSeen = aload(consXp);
              if (consSeen < need2){ if(--budget<0){dead=1;break;} __builtin_amdgcn_s_sleep(2); }
            }
          }
        }
        __syncthreads();
        if (dead) break;
      }
      // issue: prefetch slot t+1 operand
      i32x4 stg; bf16x8 vnext;
      const bool havePf = (t+1 < TT);
      if (havePf){
        if (l > 0){
          stg = ld_coh_b128(hr + (size_t)((t+1)&(RH-1))*16*256 + sm*256 + sc*8);
        } else {
          const int tok = p.tokens[(size_t)(g*16+sm)*TT + (t+1)];
          const float* er = p.emb + (size_t)tok*256 + sc*8;
          const float4 u0 = *(const float4*)er;
          const float4 u1 = *(const float4*)(er+4);
          vnext[0]=(__bf16)u0.x; vnext[1]=(__bf16)u0.y; vnext[2]=(__bf16)u0.z; vnext[3]=(__bf16)u0.w;
          vnext[4]=(__bf16)u1.x; vnext[5]=(__bf16)u1.y; vnext[6]=(__bf16)u1.z; vnext[7]=(__bf16)u1.w;
        }
      }
      // publish (fire-and-forget; data was drained at this boundary's barrier)
      if (bnd && tid == 0 && t > 0){
        astore(prodXp, (uint32_t)t);                 // slots < t complete
        if (l > 0) astore(consH, (uint32_t)t);       // h slots < t retired
      }
      // MFMA from sbuf[t&1]
      const unsigned short* hsrc = sbuf[t&1];
      f32x4 acc[6];
      #pragma unroll
      for (int nt=0; nt<6; ++nt) acc[nt] = (f32x4){bias[nt],bias[nt],bias[nt],bias[nt]};
      #pragma unroll
      for (int kt=0; kt<8; ++kt){
        const bf16x8 a = *(const bf16x8*)&hsrc[(lc*256 + kt*32 + lg*8) ^ ((lc&7)<<3)];
        #pragma unroll
        for (int nt=0; nt<6; ++nt)
          acc[nt] = __builtin_amdgcn_mfma_f32_16x16x32_bf16(a, wx[nt][kt], acc[nt], 0, 0, 0);
      }
      // store xp slot t (coherent 8B per tile; drained at a later boundary)
      __bf16* dst = xr + (size_t)(t&(RX-1))*768*16;
      #pragma unroll
      for (int nt=0; nt<6; ++nt){
        const int col = w*96 + nt*16 + lc;
        st_coh_b64(dst + col*16 + lg*4, pk4(acc[nt]));
      }
      // stage-write slot t+1 into sbuf[(t+1)&1]
      if (havePf){
        if (l > 0){
          if (bnd && t > 0) { WAITVM(8); }   // allow 2 pubs + 6 stores outstanding
          else             { WAITVM(6); }   // allow 6 stores outstanding
          *(i32x4*)&sbuf[(t+1)&1][sidx] = stg;
        } else {
          *(bf16x8*)&sbuf[(t+1)&1][sidx] = vnext;   // compiler-managed waits
        }
      }
      BARRIER_LGKM();
    }
    __syncthreads();
    if (tid == 0 && !dead){
      astore(prodXp, (uint32_t)TT);
      if (l > 0) astore(consH, (uint32_t)TT);
    }
  } else {
    // ---------------- REC stage: rec = h @ Wh (+bh for hh); gates; h update ----------------
    const float* W = p.Wh[l];
    bf16x8 wh[6][8];   // wave owns hidden slice [w*32,w*32+32): nt=2*G+q, G:0=z,1=r,2=hh
    #pragma unroll
    for (int nt=0; nt<6; ++nt){
      const int col = 256*(nt>>1) + w*32 + 16*(nt&1) + lc;
      #pragma unroll
      for (int kt=0; kt<8; ++kt){
        const int k0 = kt*32 + lg*8;
        bf16x8 v;
        #pragma unroll
        for (int e=0; e<8; ++e) v[e] = (__bf16)W[(size_t)(k0+e)*768 + col];
        wh[nt][kt] = v;
      }
    }
    float bhh[2];
    #pragma unroll
    for (int q=0; q<2; ++q) bhh[q] = p.bh[l][512 + w*32 + 16*q + lc];

    uint32_t* prodXp = flagp(p.ws, 0, g, l);
    uint32_t* prodH  = (l<3) ? flagp(p.ws, 1, g, l) : nullptr;
    uint32_t* consXp = flagp(p.ws, 2, g, l);
    uint32_t* consH  = (l<3) ? flagp(p.ws, 3, g, l) : nullptr;
    const __bf16* xr = (const __bf16*)(p.ws + WS_XP_OFF) + (size_t)(g*4+l)*XPRING_E;
    __bf16* hrw = (l<3) ? ((__bf16*)(p.ws + WS_H_OFF) + (size_t)(g*4+l)*HRING_E) : nullptr;
    float* hf = (float*)(p.ws + WS_HF_OFF);

    for (int i=tid; i<2048; i+=512) ((uint32_t*)sbuf[0])[i] = 0;  // h(-1)=0
    f32x4 hprev[2] = {(f32x4){0.f,0.f,0.f,0.f},(f32x4){0.f,0.f,0.f,0.f}};
    uint32_t consSeen = 0, prodSeen = 0;

    // prologue: prefetch xp slot 0
    if (tid == 0){
      while (prodSeen < 1u){
        prodSeen = aload(prodXp);
        if (prodSeen < 1u){ if(--budget<0){dead=1;break;} __builtin_amdgcn_s_sleep(2); }
      }
    }
    __syncthreads();
    unsigned long long xpc[6], xpn[6];
    if (!dead){
      #pragma unroll
      for (int nt=0; nt<6; ++nt){
        const int col = 256*(nt>>1) + w*32 + 16*(nt&1) + lc;
        xpc[nt] = ld_coh_b64(xr + col*16 + lg*4);
      }
    }

    for (int t=0; t<TT; ++t){
      const bool bnd = (t & (CH-1)) == 0;
      if (bnd){
        __syncthreads();           // drains aged exports/prefetches
        if (tid == 0){
          const uint32_t need = (uint32_t)((t+CH+1 < TT) ? t+CH+1 : TT);
          while (prodSeen < need){
            prodSeen = aload(prodXp);
            if (prodSeen < need){ if(--budget<0){dead=1;break;} __builtin_amdgcn_s_sleep(2); }
          }
          if (l < 3 && t + CH - 1 > RH && !dead){
            const uint32_t need2 = (uint32_t)(t + CH - 1 - RH);
            while (consSeen < need2){
              consSeen = aload(consH);
              if (consSeen < need2){ if(--budget<0){dead=1;break;} __builtin_amdgcn_s_sleep(2); }
            }
          }
        }
        __syncthreads();
        if (dead) break;
        if (tid == 0 && t > 0){
          astore(consXp, (uint32_t)t);                  // xp slots < t retired
          if (l < 3) astore(prodH, (uint32_t)(t-1));    // h slots <= t-2 ready
        }
      }
      const unsigned short* hsrc = sbuf[t&1];           // h(t-1)
      // issue: export h(t-1); prefetch xp slot t+1
      if (l < 3 && t > 0){
        const i32x4 ev = *(const i32x4*)&hsrc[(lc*256 + w*32 + lg*8) ^ ((lc&7)<<3)];
        st_coh_b128(hrw + (size_t)((t-1)&(RH-1))*16*256 + lc*256 + w*32 + lg*8, ev);
      }
      if (t+1 < TT){
        const __bf16* xb = xr + (size_t)((t+1)&(RX-1))*768*16;
        #pragma unroll
        for (int nt=0; nt<6; ++nt){
          const int col = 256*(nt>>1) + w*32 + 16*(nt&1) + lc;
          xpn[nt] = ld_coh_b64(xb + col*16 + lg*4);
        }
      }
      // MFMA over K=256
      f32x4 acc[6];
      #pragma unroll
      for (int nt=0; nt<6; ++nt) acc[nt] = (f32x4){0.f,0.f,0.f,0.f};
      #pragma unroll
      for (int kt=0; kt<8; ++kt){
        const bf16x8 a = *(const bf16x8*)&hsrc[(lc*256 + kt*32 + lg*8) ^ ((lc&7)<<3)];
        #pragma unroll
        for (int nt=0; nt<6; ++nt)
          acc[nt] = __builtin_amdgcn_mfma_f32_16x16x32_bf16(a, wh[nt][kt], acc[nt], 0, 0, 0);
      }
      // wait for xpc (prefetched >=1 step ago; boundary steps already drained)
      if (!bnd){
        if (t+1 < TT){ if (l < 3) { WAITVM(7); } else { WAITVM(6); } }
        else         { if (l < 3) { WAITVM(1); } else { WAITVM(0); } }
      }
      __builtin_amdgcn_sched_barrier(0);
      // gates: z = sig(xz+rz), r = sig(xr+rr), hh = tanh(xh + r*(rh+bh_h))
      #pragma unroll
      for (int q=0; q<2; ++q){
        const f32x4 xz = up4(xpc[q]);
        const f32x4 xr_ = up4(xpc[2+q]);
        const f32x4 xh = up4(xpc[4+q]);
        #pragma unroll
        for (int e=0; e<4; ++e){
          const float z = sigf(xz[e] + acc[q][e]);
          const float r = sigf(xr_[e] + acc[2+q][e]);
          const float c = tanh_(xh[e] + r*(acc[4+q][e] + bhh[q]));
          hprev[q][e] = z*hprev[q][e] + (1.f - z)*c;
        }
      }
      // write h(t) into sbuf[(t+1)&1] (other buffer: no read/write conflict)
      unsigned short* hdst = sbuf[(t+1)&1];
      #pragma unroll
      for (int q=0; q<2; ++q){
        const int j = w*32 + 16*q + lc;
        #pragma unroll
        for (int r2=0; r2<4; ++r2){
          const int m = lg*4 + r2;
          hdst[(m*256 + j) ^ ((m&7)<<3)] = f2b(hprev[q][r2]);
        }
      }
      if (l == 3 && t == TT-1){
        #pragma unroll
        for (int q=0; q<2; ++q){
          const int j = w*32 + 16*q + lc;
          #pragma unroll
          for (int r2=0; r2<4; ++r2) hf[(size_t)(g*16 + lg*4 + r2)*256 + j] = hprev[q][r2];
        }
      }
      BARRIER_LGKM();
      #pragma unroll
      for (int nt=0; nt<6; ++nt) xpc[nt] = xpn[nt];
    }
    if (!dead){
      if (l < 3){
        // export final h(TT-1) from sbuf[TT&1] = sbuf[0]
        const i32x4 ev = *(const i32x4*)&sbuf[0][(lc*256 + w*32 + lg*8) ^ ((lc&7)<<3)];
        st_coh_b128(hrw + (size_t)((TT-1)&(RH-1))*16*256 + lc*256 + w*32 + lg*8, ev);
      }
      __syncthreads();   // drain exports + hf
      if (tid == 0){
        if (l < 3) astore(prodH, (uint32_t)TT);
        astore(consXp, (uint32_t)TT);
      }
    }
  }
}

// Final head: relu(h @ Wd1 + bd1) @ Wd2 + bd2 -> sigmoid. One block per sample.
__global__ __launch_bounds__(256) void dense_head(const float* __restrict__ hf,
    const float* __restrict__ Wd1, const float* __restrict__ bd1,
    const float* __restrict__ Wd2, const float* __restrict__ bd2,
    float* __restrict__ out){
  const int m = blockIdx.x;
  const int n = threadIdx.x;
  __shared__ float hs[256];
  __shared__ float red[256];
  hs[n] = hf[(size_t)m*256 + n];
  __syncthreads();
  float acc = bd1[n];
  #pragma unroll 8
  for (int k=0; k<256; ++k) acc = fmaf(hs[k], Wd1[(size_t)k*256 + n], acc);
  const float rl = fmaxf(acc, 0.f);
  red[n] = rl * Wd2[n];
  __syncthreads();
  for (int off=128; off>0; off>>=1){
    if (n < off) red[n] += red[n+off];
    __syncthreads();
  }
  if (n == 0) out[m] = 1.f/(1.f + __expf(-(red[0] + bd2[0])));
}

extern "C" void kernel_launch(void* const* d_in, const int* in_sizes, int n_in,
                              void* d_out, int out_size, void* d_ws, size_t ws_size,
                              hipStream_t stream){
  (void)in_sizes; (void)n_in; (void)out_size; (void)ws_size;
  Params p;
  p.tokens = (const int*)d_in[0];
  p.emb    = (const float*)d_in[1];
  for (int l=0; l<4; ++l){
    p.Wx[l] = (const float*)d_in[2+4*l];
    p.Wh[l] = (const float*)d_in[3+4*l];
    p.bx[l] = (const float*)d_in[4+4*l];
    p.bh[l] = (const float*)d_in[5+4*l];
  }
  p.ws = (uint8_t*)d_ws;
  hipMemsetAsync(d_ws, 0, FLAGS_BYTES, stream);           // zero flags each launch
  gru_pipeline<<<dim3(64), dim3(512), 0, stream>>>(p);
  dense_head<<<dim3(128), dim3(256), 0, stream>>>(
      (const float*)((uint8_t*)d_ws + WS_HF_OFF),
      (const float*)d_in[18], (const float*)d_in[19],
      (const float*)d_in[20], (const float*)d_in[21],
      (float*)d_out);
}